// Round 7
// baseline (90.839 us; speedup 1.0000x reference)
//
#include <hip/hip_runtime.h>
#include <hip/hip_bf16.h>
#include <stdint.h>

// Problem constants (fixed by setup_inputs)
#define KC   256      // concepts
#define DD   256      // feature dim
#define NPROT 1024    // KC*M
#define NQ   32768    // B*KC

// ws layout (bytes); ws_size = 256 MB. Total used ~2.6 MB.
#define OFF_TOT  0                        // float
#define OFF_CNT  8                        // float
#define OFF_PN   256                      // bf16 protos k-major: [16 kslabs][1024 rows][32B] (512 KB)
#define OFF_ACC  524544                   // float[32768][2 chunks][4 waves][2] = 2 MB, collision-free

#define LN2F    0.69314718055994531f
#define C10L2E  14.426950408889634f       // 10 * log2(e): folds 1/T into exp2 domain

typedef __bf16 bf16x8 __attribute__((ext_vector_type(8)));
typedef float  f32x16 __attribute__((ext_vector_type(16)));

static __device__ __forceinline__ unsigned short f2bf(float x) {
  __hip_bfloat16 h = __float2bfloat16(x);
  return __builtin_bit_cast(unsigned short, h);
}

// ---------------- Kernel 1: normalize protos -> bf16 k-major; zero scalars ----------------
__global__ __launch_bounds__(256) void prep_k(const float* __restrict__ protos,
                                              unsigned char* __restrict__ ws) {
  if (blockIdx.x == 0 && threadIdx.x == 0) {
    *(float*)(ws + OFF_TOT) = 0.0f;
    *(float*)(ws + OFF_CNT) = 0.0f;
  }
  const int w = threadIdx.x >> 6, lane = threadIdx.x & 63;
  const int r = blockIdx.x * 4 + w;                  // 256 blocks * 4 = 1024 rows
  const float4 v = ((const float4*)protos)[r * 64 + lane];
  float ss = v.x*v.x + v.y*v.y + v.z*v.z + v.w*v.w;
#pragma unroll
  for (int m = 1; m < 64; m <<= 1) ss += __shfl_xor(ss, m, 64);
  const float sc = 1.0f / fmaxf(sqrtf(ss), 1e-12f);
  uint2 p;
  p.x = (unsigned)f2bf(v.x * sc) | ((unsigned)f2bf(v.y * sc) << 16);
  p.y = (unsigned)f2bf(v.z * sc) | ((unsigned)f2bf(v.w * sc) << 16);
  // element e = lane*4.. -> slab = lane>>2, byte in slab-row = (lane&3)*8
  *(uint2*)(ws + OFF_PN + (lane >> 2) * 32768 + r * 32 + (lane & 3) * 8) = p;
}

// ---------------- Kernel 2: fused normalize(Q) + GEMM + exp2/pos partials ----------------
// grid: 256 tiles (128 queries) x 2 chunks (512 protos) = 512 blocks = 2/CU, 256 threads
__global__ __launch_bounds__(256, 2) void main_k(const float* __restrict__ lv,
                                                 unsigned char* __restrict__ ws) {
  __shared__ __align__(16) unsigned char Aq[128 * 512];  // 128 query rows, bf16, swizzled (64 KB)

  const int tid  = threadIdx.x;
  const int w    = tid >> 6;        // wave 0..3
  const int lane = tid & 63;
  const int hi   = lane >> 5;
  const int l31  = lane & 31;

  const int tile = blockIdx.x >> 1;          // 0..255 (128 queries each)
  const int c    = blockIdx.x & 1;           // proto chunk of 512 rows

  // A-fragment base: proto rows c*512 + w*128 + pass*32 + l31, 16B piece hi
  // addr(step s = pass*16 + k) = pn + (s&15)*32768 + (s>>4)*1024
  const unsigned char* pn = ws + OFF_PN + (c * 512 + w * 128 + l31) * 32 + hi * 16;

  // depth-8 A prefetch ring, issued BEFORE the normalize phase (hides L2 latency under it)
  bf16x8 pa[8];
#pragma unroll
  for (int p = 0; p < 8; ++p) pa[p] = *(const bf16x8*)(pn + p * 32768);

  // ---- Phase 1: load + L2-normalize 128 query rows -> swizzled bf16 LDS ----
  // 16-lane group per row, 8 rows per group (proven pattern from r6 prep_k)
  const int grp = tid >> 4, sub = tid & 15;
  for (int t = 0; t < 8; ++t) {
    const int r = grp * 8 + t;               // row in tile 0..127
    const int q = tile * 128 + r;
    float4 vv[4];
#pragma unroll
    for (int u = 0; u < 4; ++u) vv[u] = ((const float4*)lv)[q * 64 + u * 16 + sub];
    float ss = 0.0f;
#pragma unroll
    for (int u = 0; u < 4; ++u)
      ss += vv[u].x*vv[u].x + vv[u].y*vv[u].y + vv[u].z*vv[u].z + vv[u].w*vv[u].w;
#pragma unroll
    for (int m = 1; m < 16; m <<= 1) ss += __shfl_xor(ss, m, 64);
    const float sc = 1.0f / fmaxf(sqrtf(ss), 1e-12f);
    const int swz = ((r & 7) << 4) ^ (((r >> 3) & 3) << 7);
#pragma unroll
    for (int u = 0; u < 4; ++u) {
      uint2 p;
      p.x = (unsigned)f2bf(vv[u].x * sc) | ((unsigned)f2bf(vv[u].y * sc) << 16);
      p.y = (unsigned)f2bf(vv[u].z * sc) | ((unsigned)f2bf(vv[u].w * sc) << 16);
      *(uint2*)(Aq + r * 512 + ((u * 128 + sub * 8) ^ swz)) = p;
    }
  }
  __syncthreads();

  float l_acc[4] = {0.f, 0.f, 0.f, 0.f};
  float p_acc[4] = {0.f, 0.f, 0.f, 0.f};
  const int bswz = ((l31 & 7) << 4) ^ (((l31 >> 3) & 3) << 7);

  for (int pass = 0; pass < 4; ++pass) {     // 4 passes of 32 proto rows per wave
    f32x16 acc[4];
#pragma unroll
    for (int j = 0; j < 4; ++j)
#pragma unroll
      for (int t = 0; t < 16; ++t) acc[j][t] = 0.0f;

#pragma unroll
    for (int k = 0; k < 16; ++k) {
      const bf16x8 a = pa[k & 7];            // s&7 == k&7 since 16 % 8 == 0
      if (pass < 3 || k < 8)                 // prefetch step s+8 (guarded at the tail)
        pa[k & 7] = *(const bf16x8*)(pn + ((k + 8) & 15) * 32768
                                        + (pass + (k >= 8 ? 1 : 0)) * 1024);
      const int bc = (k * 32 + hi * 16) ^ bswz;
      bf16x8 b[4];
#pragma unroll
      for (int j = 0; j < 4; ++j)
        b[j] = *(const bf16x8*)(Aq + (j * 32 + l31) * 512 + bc);
#pragma unroll
      for (int j = 0; j < 4; ++j)
        acc[j] = __builtin_amdgcn_mfma_f32_32x32x16_bf16(a, b[j], acc[j], 0, 0, 0);
    }

    // ---- epilogue for this pass: y = sim*10*log2e; L += 2^y; P += y on positives ----
    const int r4base = c * 128 + w * 32 + pass * 8 + hi;   // proto row>>2 = r4base + 2*g
#pragma unroll
    for (int j = 0; j < 4; ++j) {
      const int kq = (tile * 128 + j * 32 + l31) & (KC - 1);
      float l4[4] = {0.f, 0.f, 0.f, 0.f};
      float p4[4] = {0.f, 0.f, 0.f, 0.f};
#pragma unroll
      for (int g = 0; g < 4; ++g) {
        const float pm = (r4base + 2 * g == kq) ? 1.0f : 0.0f;
#pragma unroll
        for (int t = 0; t < 4; ++t) {
          const float y = acc[j][g * 4 + t] * C10L2E;
          l4[t] += __builtin_amdgcn_exp2f(y);
          p4[t] = fmaf(pm, y, p4[t]);
        }
      }
      l_acc[j] += (l4[0] + l4[1]) + (l4[2] + l4[3]);
      p_acc[j] += (p4[0] + p4[1]) + (p4[2] + p4[3]);
    }
  }

  // combine the two row-half lanes (lane ^ 32); ONE plain store per (q, chunk, wave)
#pragma unroll
  for (int j = 0; j < 4; ++j) {
    l_acc[j] += __shfl_xor(l_acc[j], 32, 64);
    p_acc[j] += __shfl_xor(p_acc[j], 32, 64);
  }
  if (hi == 0) {
    float* accb = (float*)(ws + OFF_ACC);
#pragma unroll
    for (int j = 0; j < 4; ++j) {
      const int q = tile * 128 + j * 32 + l31;
      float2 v2; v2.x = l_acc[j]; v2.y = p_acc[j];
      *(float2*)(accb + q * 16 + c * 8 + w * 2) = v2;    // [q][c][w][2], collision-free
    }
  }
}

// ---------------- Kernel 3: per-query contribution + count, grid sum into ws ----------------
__global__ __launch_bounds__(256) void finish1_k(const int* __restrict__ gt,
                                                 unsigned char* __restrict__ ws) {
  __shared__ float accs[4], accn[4];
  const int i = blockIdx.x * 256 + threadIdx.x;   // 128 blocks -> 32768
  float contrib = 0.0f, cnt = 0.0f;
  if (gt[i] == 1) {
    const float* a = (const float*)(ws + OFF_ACC) + i * 16;  // 8 {l,p} pairs
    float L = 0.0f, P = 0.0f;
#pragma unroll
    for (int u = 0; u < 4; ++u) {
      const float4 v = *(const float4*)(a + u * 4);
      L += v.x + v.z;
      P += v.y + v.w;
    }
    contrib = LN2F * (4.0f * __builtin_amdgcn_logf(L) - P);  // v_log_f32 = log2
    cnt = 1.0f;
  }
#pragma unroll
  for (int m = 1; m < 64; m <<= 1) {
    contrib += __shfl_xor(contrib, m, 64);
    cnt     += __shfl_xor(cnt, m, 64);
  }
  if ((threadIdx.x & 63) == 0) { accs[threadIdx.x >> 6] = contrib; accn[threadIdx.x >> 6] = cnt; }
  __syncthreads();
  if (threadIdx.x == 0) {
    atomicAdd((float*)(ws + OFF_TOT), (accs[0] + accs[1]) + (accs[2] + accs[3]));
    atomicAdd((float*)(ws + OFF_CNT), (accn[0] + accn[1]) + (accn[2] + accn[3]));
  }
}

// ---------------- Kernel 4: final divide ----------------
__global__ __launch_bounds__(64) void finish2_k(const unsigned char* __restrict__ ws,
                                                float* __restrict__ out) {
  if (threadIdx.x == 0) {
    const float total = *(const float*)(ws + OFF_TOT);
    const float cnt   = *(const float*)(ws + OFF_CNT);
    out[0] = (cnt > 0.0f) ? total / (4.0f * cnt) : 0.0f;
  }
}

extern "C" void kernel_launch(void* const* d_in, const int* in_sizes, int n_in,
                              void* d_out, int out_size, void* d_ws, size_t ws_size,
                              hipStream_t stream) {
  const float* lv     = (const float*)d_in[0];   // (128,256,256) f32
  const float* protos = (const float*)d_in[1];   // (1024,256,1,1) f32
  const int*   gt     = (const int*)d_in[2];     // (128,256) i32
  (void)in_sizes; (void)n_in; (void)out_size; (void)ws_size;
  unsigned char* ws = (unsigned char*)d_ws;

  prep_k<<<256, 256, 0, stream>>>(protos, ws);
  main_k<<<512, 256, 0, stream>>>(lv, ws);
  finish1_k<<<128, 256, 0, stream>>>(gt, ws);
  finish2_k<<<1, 64, 0, stream>>>(ws, (float*)d_out);
}

// Round 8
// 87.891 us; speedup vs baseline: 1.0335x; 1.0335x over previous
//
#include <hip/hip_runtime.h>
#include <hip/hip_bf16.h>
#include <stdint.h>

// Problem constants (fixed by setup_inputs)
#define KC   256      // concepts
#define DD   256      // feature dim
#define NPROT 1024    // KC*M
#define NQ   32768    // B*KC

// ws layout (bytes); ws_size = 256 MB. Total used ~2.6 MB.
#define OFF_TOT  0                        // float
#define OFF_CNT  8                        // float
#define OFF_PN   256                      // bf16 protos k-major: [16 kslabs][1024 rows][32B] (512 KB)
#define OFF_ACC  524544                   // float[32768][2 chunks][4 waves][2] = 2 MB, collision-free

#define LN2F    0.69314718055994531f
#define C10L2E  14.426950408889634f       // 10 * log2(e): folds 1/T into exp2 domain

typedef __bf16 bf16x8 __attribute__((ext_vector_type(8)));
typedef float  f32x16 __attribute__((ext_vector_type(16)));

static __device__ __forceinline__ unsigned short f2bf(float x) {
  __hip_bfloat16 h = __float2bfloat16(x);
  return __builtin_bit_cast(unsigned short, h);
}

// ---------------- Kernel 1: normalize protos -> bf16 k-major; zero scalars ----------------
__global__ __launch_bounds__(256) void prep_k(const float* __restrict__ protos,
                                              unsigned char* __restrict__ ws) {
  if (blockIdx.x == 0 && threadIdx.x == 0) {
    *(float*)(ws + OFF_TOT) = 0.0f;
    *(float*)(ws + OFF_CNT) = 0.0f;
  }
  const int w = threadIdx.x >> 6, lane = threadIdx.x & 63;
  const int r = blockIdx.x * 4 + w;                  // 256 blocks * 4 = 1024 rows
  const float4 v = ((const float4*)protos)[r * 64 + lane];
  float ss = v.x*v.x + v.y*v.y + v.z*v.z + v.w*v.w;
#pragma unroll
  for (int m = 1; m < 64; m <<= 1) ss += __shfl_xor(ss, m, 64);
  const float sc = 1.0f / fmaxf(sqrtf(ss), 1e-12f);
  uint2 p;
  p.x = (unsigned)f2bf(v.x * sc) | ((unsigned)f2bf(v.y * sc) << 16);
  p.y = (unsigned)f2bf(v.z * sc) | ((unsigned)f2bf(v.w * sc) << 16);
  // element e = lane*4.. -> slab = lane>>2, byte in slab-row = (lane&3)*8
  *(uint2*)(ws + OFF_PN + (lane >> 2) * 32768 + r * 32 + (lane & 3) * 8) = p;
}

// ---------------- Kernel 2: fused normalize(Q) + GEMM + exp2/pos partials ----------------
// grid: 512 tiles (64 queries) x 2 chunks (512 protos) = 1024 blocks = 4/CU, 256 threads
__global__ __launch_bounds__(256, 4) void main_k(const float* __restrict__ lv,
                                                 unsigned char* __restrict__ ws) {
  __shared__ __align__(16) unsigned char Aq[64 * 512];  // 64 query rows, bf16, swizzled (32 KB)

  const int tid  = threadIdx.x;
  const int w    = tid >> 6;        // wave 0..3
  const int lane = tid & 63;
  const int hi   = lane >> 5;
  const int l31  = lane & 31;

  const int tile = blockIdx.x >> 1;          // 0..511 (64 queries each)
  const int c    = blockIdx.x & 1;           // proto chunk of 512 rows

  // A-fragment base: proto rows c*512 + w*128 + pass*32 + l31, 16B piece hi
  // addr(step s = pass*16 + k) = pn + (s&15)*32768 + (s>>4)*1024
  const unsigned char* pn = ws + OFF_PN + (c * 512 + w * 128 + l31) * 32 + hi * 16;

  // depth-8 A prefetch ring, issued BEFORE the normalize phase (L2 latency hides under it)
  bf16x8 pa[8];
#pragma unroll
  for (int p = 0; p < 8; ++p) pa[p] = *(const bf16x8*)(pn + p * 32768);

  // ---- Phase 1: load + L2-normalize 64 query rows -> swizzled bf16 LDS ----
  // 16-lane group per row, 4 rows per group (proven r4 pattern)
  const int grp = tid >> 4, sub = tid & 15;
#pragma unroll
  for (int t = 0; t < 4; ++t) {
    const int r = grp * 4 + t;               // row in tile 0..63
    const int q = tile * 64 + r;
    float4 vv[4];
#pragma unroll
    for (int u = 0; u < 4; ++u) vv[u] = ((const float4*)lv)[q * 64 + u * 16 + sub];
    float ss = 0.0f;
#pragma unroll
    for (int u = 0; u < 4; ++u)
      ss += vv[u].x*vv[u].x + vv[u].y*vv[u].y + vv[u].z*vv[u].z + vv[u].w*vv[u].w;
#pragma unroll
    for (int m = 1; m < 16; m <<= 1) ss += __shfl_xor(ss, m, 64);
    const float sc = 1.0f / fmaxf(sqrtf(ss), 1e-12f);
    const int swz = ((r & 7) << 4) ^ (((r >> 3) & 3) << 7);
#pragma unroll
    for (int u = 0; u < 4; ++u) {
      uint2 p;
      p.x = (unsigned)f2bf(vv[u].x * sc) | ((unsigned)f2bf(vv[u].y * sc) << 16);
      p.y = (unsigned)f2bf(vv[u].z * sc) | ((unsigned)f2bf(vv[u].w * sc) << 16);
      *(uint2*)(Aq + r * 512 + ((u * 128 + sub * 8) ^ swz)) = p;
    }
  }
  __syncthreads();

  float l_acc[2] = {0.f, 0.f};
  float p_acc[2] = {0.f, 0.f};
  const int bswz = ((l31 & 7) << 4) ^ (((l31 >> 3) & 3) << 7);  // rows l31 / 32+l31 identical

#pragma unroll 1
  for (int pass = 0; pass < 4; ++pass) {     // 4 passes of 32 proto rows per wave
    f32x16 acc0, acc1;
#pragma unroll
    for (int t = 0; t < 16; ++t) { acc0[t] = 0.0f; acc1[t] = 0.0f; }

#pragma unroll
    for (int k = 0; k < 16; ++k) {
      const bf16x8 a = pa[k & 7];            // ring: (pass*16+k)&7 == k&7
      // prefetch step s+8 unconditionally; tail prefetches land in unused ws bytes
      pa[k & 7] = *(const bf16x8*)(pn + ((k + 8) & 15) * 32768
                                      + (pass + (k >= 8 ? 1 : 0)) * 1024);
      const int bc = (k * 32 + hi * 16) ^ bswz;
      const bf16x8 b0 = *(const bf16x8*)(Aq + l31 * 512 + bc);
      const bf16x8 b1 = *(const bf16x8*)(Aq + (32 + l31) * 512 + bc);
      acc0 = __builtin_amdgcn_mfma_f32_32x32x16_bf16(a, b0, acc0, 0, 0, 0);
      acc1 = __builtin_amdgcn_mfma_f32_32x32x16_bf16(a, b1, acc1, 0, 0, 0);
    }

    // ---- epilogue for this pass: y = sim*10*log2e; L += 2^y; P += y on positives ----
    const int r4base = c * 128 + w * 32 + pass * 8 + hi;   // proto row>>2 = r4base + 2*g
#pragma unroll
    for (int j = 0; j < 2; ++j) {
      const int kq = (tile * 64 + j * 32 + l31) & (KC - 1);
      float l4[4] = {0.f, 0.f, 0.f, 0.f};
      float p4[4] = {0.f, 0.f, 0.f, 0.f};
#pragma unroll
      for (int g = 0; g < 4; ++g) {
        const float pm = (r4base + 2 * g == kq) ? 1.0f : 0.0f;
#pragma unroll
        for (int t = 0; t < 4; ++t) {
          const float y = ((j == 0) ? acc0[g * 4 + t] : acc1[g * 4 + t]) * C10L2E;
          l4[t] += __builtin_amdgcn_exp2f(y);
          p4[t] = fmaf(pm, y, p4[t]);
        }
      }
      l_acc[j] += (l4[0] + l4[1]) + (l4[2] + l4[3]);
      p_acc[j] += (p4[0] + p4[1]) + (p4[2] + p4[3]);
    }
  }

  // combine the two row-half lanes (lane ^ 32); ONE plain store per (q, chunk, wave)
#pragma unroll
  for (int j = 0; j < 2; ++j) {
    l_acc[j] += __shfl_xor(l_acc[j], 32, 64);
    p_acc[j] += __shfl_xor(p_acc[j], 32, 64);
  }
  if (hi == 0) {
    float* accb = (float*)(ws + OFF_ACC);
#pragma unroll
    for (int j = 0; j < 2; ++j) {
      const int q = tile * 64 + j * 32 + l31;
      float2 v2; v2.x = l_acc[j]; v2.y = p_acc[j];
      *(float2*)(accb + q * 16 + c * 8 + w * 2) = v2;    // [q][c][w][2], collision-free
    }
  }
}

// ---------------- Kernel 3: per-query contribution + count, grid sum into ws ----------------
__global__ __launch_bounds__(256) void finish1_k(const int* __restrict__ gt,
                                                 unsigned char* __restrict__ ws) {
  __shared__ float accs[4], accn[4];
  const int i = blockIdx.x * 256 + threadIdx.x;   // 128 blocks -> 32768
  float contrib = 0.0f, cnt = 0.0f;
  if (gt[i] == 1) {
    const float* a = (const float*)(ws + OFF_ACC) + i * 16;  // 8 {l,p} pairs
    float L = 0.0f, P = 0.0f;
#pragma unroll
    for (int u = 0; u < 4; ++u) {
      const float4 v = *(const float4*)(a + u * 4);
      L += v.x + v.z;
      P += v.y + v.w;
    }
    contrib = LN2F * (4.0f * __builtin_amdgcn_logf(L) - P);  // v_log_f32 = log2
    cnt = 1.0f;
  }
#pragma unroll
  for (int m = 1; m < 64; m <<= 1) {
    contrib += __shfl_xor(contrib, m, 64);
    cnt     += __shfl_xor(cnt, m, 64);
  }
  if ((threadIdx.x & 63) == 0) { accs[threadIdx.x >> 6] = contrib; accn[threadIdx.x >> 6] = cnt; }
  __syncthreads();
  if (threadIdx.x == 0) {
    atomicAdd((float*)(ws + OFF_TOT), (accs[0] + accs[1]) + (accs[2] + accs[3]));
    atomicAdd((float*)(ws + OFF_CNT), (accn[0] + accn[1]) + (accn[2] + accn[3]));
  }
}

// ---------------- Kernel 4: final divide ----------------
__global__ __launch_bounds__(64) void finish2_k(const unsigned char* __restrict__ ws,
                                                float* __restrict__ out) {
  if (threadIdx.x == 0) {
    const float total = *(const float*)(ws + OFF_TOT);
    const float cnt   = *(const float*)(ws + OFF_CNT);
    out[0] = (cnt > 0.0f) ? total / (4.0f * cnt) : 0.0f;
  }
}

extern "C" void kernel_launch(void* const* d_in, const int* in_sizes, int n_in,
                              void* d_out, int out_size, void* d_ws, size_t ws_size,
                              hipStream_t stream) {
  const float* lv     = (const float*)d_in[0];   // (128,256,256) f32
  const float* protos = (const float*)d_in[1];   // (1024,256,1,1) f32
  const int*   gt     = (const int*)d_in[2];     // (128,256) i32
  (void)in_sizes; (void)n_in; (void)out_size; (void)ws_size;
  unsigned char* ws = (unsigned char*)d_ws;

  prep_k<<<256, 256, 0, stream>>>(protos, ws);
  main_k<<<1024, 256, 0, stream>>>(lv, ws);
  finish1_k<<<128, 256, 0, stream>>>(gt, ws);
  finish2_k<<<1, 64, 0, stream>>>(ws, (float*)d_out);
}

// Round 9
// 62.433 us; speedup vs baseline: 1.4550x; 1.4078x over previous
//
#include <hip/hip_runtime.h>
#include <hip/hip_bf16.h>
#include <stdint.h>

// Problem constants (fixed by setup_inputs)
#define KC   256      // concepts
#define DD   256      // feature dim
#define NPROT 1024    // KC*M
#define NQ   32768    // B*KC

// ws layout (bytes); ws_size = 256 MB. Total used ~2.6 MB.
#define OFF_TOT  0                        // float
#define OFF_CNT  8                        // float
#define OFF_PN   256                      // bf16 protos k-major: [16 kslabs][1024 rows][32B] (512 KB)
#define OFF_ACC  524544                   // float2[2 chunks][4 waves][32768 q] = 2 MB, collision-free
#define ACC_STRIDE 32768                  // float2 per (c,w) plane

#define LN2F    0.69314718055994531f
#define C10L2E  14.426950408889634f       // 10 * log2(e): folds 1/T into exp2 domain

typedef __bf16 bf16x8 __attribute__((ext_vector_type(8)));
typedef float  f32x16 __attribute__((ext_vector_type(16)));

static __device__ __forceinline__ unsigned short f2bf(float x) {
  __hip_bfloat16 h = __float2bfloat16(x);
  return __builtin_bit_cast(unsigned short, h);
}

// ---------------- Kernel 1: normalize protos -> bf16 k-major; zero scalars ----------------
__global__ __launch_bounds__(256) void prep_k(const float* __restrict__ protos,
                                              unsigned char* __restrict__ ws) {
  if (blockIdx.x == 0 && threadIdx.x == 0) {
    *(float*)(ws + OFF_TOT) = 0.0f;
    *(float*)(ws + OFF_CNT) = 0.0f;
  }
  const int w = threadIdx.x >> 6, lane = threadIdx.x & 63;
  const int r = blockIdx.x * 4 + w;                  // 256 blocks * 4 = 1024 rows
  const float4 v = ((const float4*)protos)[r * 64 + lane];
  float ss = v.x*v.x + v.y*v.y + v.z*v.z + v.w*v.w;
#pragma unroll
  for (int m = 1; m < 64; m <<= 1) ss += __shfl_xor(ss, m, 64);
  const float sc = 1.0f / fmaxf(sqrtf(ss), 1e-12f);
  uint2 p;
  p.x = (unsigned)f2bf(v.x * sc) | ((unsigned)f2bf(v.y * sc) << 16);
  p.y = (unsigned)f2bf(v.z * sc) | ((unsigned)f2bf(v.w * sc) << 16);
  // element e = lane*4.. -> slab = lane>>2, byte in slab-row = (lane&3)*8
  *(uint2*)(ws + OFF_PN + (lane >> 2) * 32768 + r * 32 + (lane & 3) * 8) = p;
}

// ---------------- Kernel 2: fused normalize(Q) + GEMM + exp2/pos partials ----------------
// grid: 512 tiles (64 queries) x 2 chunks (512 protos) = 1024 blocks, 256 threads.
// NO min-waves bound: let the allocator use ~100 VGPRs (r7/r8 lesson: a forced cap
// split the unified file 64/64 and spilled ~78 regs -> 78 MB scratch writes/dispatch).
__global__ __launch_bounds__(256) void main_k(const float* __restrict__ lv,
                                              unsigned char* __restrict__ ws) {
  __shared__ __align__(16) unsigned char Aq[64 * 512];  // 64 query rows, bf16, swizzled (32 KB)

  const int tid  = threadIdx.x;
  const int w    = tid >> 6;        // wave 0..3
  const int lane = tid & 63;
  const int hi   = lane >> 5;
  const int l31  = lane & 31;

  const int tile = blockIdx.x >> 1;          // 0..511 (64 queries each)
  const int c    = blockIdx.x & 1;           // proto chunk of 512 rows

  // A-fragment base: proto rows c*512 + w*128 + pass*32 + l31, 16B piece hi
  // addr(step s = pass*16 + k) = pn + (s&15)*32768 + (s>>4)*1024
  const unsigned char* pn = ws + OFF_PN + (c * 512 + w * 128 + l31) * 32 + hi * 16;

  // depth-4 A prefetch ring (16 VGPRs), issued BEFORE the normalize phase
  bf16x8 pa[4];
#pragma unroll
  for (int p = 0; p < 4; ++p) pa[p] = *(const bf16x8*)(pn + p * 32768);

  // ---- Phase 1: load + L2-normalize 64 query rows -> swizzled bf16 LDS ----
  // 16-lane group per row, 4 rows per group (proven r4 pattern)
  const int grp = tid >> 4, sub = tid & 15;
#pragma unroll
  for (int t = 0; t < 4; ++t) {
    const int r = grp * 4 + t;               // row in tile 0..63
    const int q = tile * 64 + r;
    float4 vv[4];
#pragma unroll
    for (int u = 0; u < 4; ++u) vv[u] = ((const float4*)lv)[q * 64 + u * 16 + sub];
    float ss = 0.0f;
#pragma unroll
    for (int u = 0; u < 4; ++u)
      ss += vv[u].x*vv[u].x + vv[u].y*vv[u].y + vv[u].z*vv[u].z + vv[u].w*vv[u].w;
#pragma unroll
    for (int m = 1; m < 16; m <<= 1) ss += __shfl_xor(ss, m, 64);
    const float sc = 1.0f / fmaxf(sqrtf(ss), 1e-12f);
    const int swz = ((r & 7) << 4) ^ (((r >> 3) & 3) << 7);
#pragma unroll
    for (int u = 0; u < 4; ++u) {
      uint2 p;
      p.x = (unsigned)f2bf(vv[u].x * sc) | ((unsigned)f2bf(vv[u].y * sc) << 16);
      p.y = (unsigned)f2bf(vv[u].z * sc) | ((unsigned)f2bf(vv[u].w * sc) << 16);
      *(uint2*)(Aq + r * 512 + ((u * 128 + sub * 8) ^ swz)) = p;
    }
  }
  __syncthreads();

  float l_acc[2] = {0.f, 0.f};
  float p_acc[2] = {0.f, 0.f};
  const int bswz = ((l31 & 7) << 4) ^ (((l31 >> 3) & 3) << 7);  // rows l31 / 32+l31 identical

#pragma unroll 1
  for (int pass = 0; pass < 4; ++pass) {     // 4 passes of 32 proto rows per wave
    f32x16 acc0, acc1;
#pragma unroll
    for (int t = 0; t < 16; ++t) { acc0[t] = 0.0f; acc1[t] = 0.0f; }

#pragma unroll
    for (int k = 0; k < 16; ++k) {
      const bf16x8 a = pa[k & 3];            // ring: (pass*16+k)&3 == k&3
      // prefetch step s+4 unconditionally; tail prefetches read harmless ws bytes
      pa[k & 3] = *(const bf16x8*)(pn + ((k + 4) & 15) * 32768
                                      + (pass + (k >= 12 ? 1 : 0)) * 1024);
      const int bc = (k * 32 + hi * 16) ^ bswz;
      const bf16x8 b0 = *(const bf16x8*)(Aq + l31 * 512 + bc);
      const bf16x8 b1 = *(const bf16x8*)(Aq + (32 + l31) * 512 + bc);
      acc0 = __builtin_amdgcn_mfma_f32_32x32x16_bf16(a, b0, acc0, 0, 0, 0);
      acc1 = __builtin_amdgcn_mfma_f32_32x32x16_bf16(a, b1, acc1, 0, 0, 0);
    }

    // ---- epilogue for this pass: y = sim*10*log2e; L += 2^y; P += y on positives ----
    const int r4base = c * 128 + w * 32 + pass * 8 + hi;   // proto row>>2 = r4base + 2*g
#pragma unroll
    for (int j = 0; j < 2; ++j) {
      const int kq = (tile * 64 + j * 32 + l31) & (KC - 1);
      float l4[4] = {0.f, 0.f, 0.f, 0.f};
      float p4[4] = {0.f, 0.f, 0.f, 0.f};
#pragma unroll
      for (int g = 0; g < 4; ++g) {
        const float pm = (r4base + 2 * g == kq) ? 1.0f : 0.0f;
#pragma unroll
        for (int t = 0; t < 4; ++t) {
          const float y = ((j == 0) ? acc0[g * 4 + t] : acc1[g * 4 + t]) * C10L2E;
          l4[t] += __builtin_amdgcn_exp2f(y);
          p4[t] = fmaf(pm, y, p4[t]);
        }
      }
      l_acc[j] += (l4[0] + l4[1]) + (l4[2] + l4[3]);
      p_acc[j] += (p4[0] + p4[1]) + (p4[2] + p4[3]);
    }
  }

  // combine the two row-half lanes (lane ^ 32); ONE plain store per (q, chunk, wave).
  // ACC layout [c][w][q]: lane-consecutive float2 -> fully coalesced 8B stores.
#pragma unroll
  for (int j = 0; j < 2; ++j) {
    l_acc[j] += __shfl_xor(l_acc[j], 32, 64);
    p_acc[j] += __shfl_xor(p_acc[j], 32, 64);
  }
  if (hi == 0) {
    float2* accb = (float2*)(ws + OFF_ACC) + (c * 4 + w) * ACC_STRIDE;
#pragma unroll
    for (int j = 0; j < 2; ++j) {
      const int q = tile * 64 + j * 32 + l31;
      float2 v2; v2.x = l_acc[j]; v2.y = p_acc[j];
      accb[q] = v2;
    }
  }
}

// ---------------- Kernel 3: per-query contribution + count, grid sum into ws ----------------
__global__ __launch_bounds__(256) void finish1_k(const int* __restrict__ gt,
                                                 unsigned char* __restrict__ ws) {
  __shared__ float accs[4], accn[4];
  const int i = blockIdx.x * 256 + threadIdx.x;   // 128 blocks -> 32768
  float contrib = 0.0f, cnt = 0.0f;
  if (gt[i] == 1) {
    const float2* a = (const float2*)(ws + OFF_ACC);
    float L = 0.0f, P = 0.0f;
#pragma unroll
    for (int u = 0; u < 8; ++u) {            // 8 (c,w) planes, coalesced across threads
      const float2 v = a[u * ACC_STRIDE + i];
      L += v.x; P += v.y;
    }
    contrib = LN2F * (4.0f * __builtin_amdgcn_logf(L) - P);  // v_log_f32 = log2
    cnt = 1.0f;
  }
#pragma unroll
  for (int m = 1; m < 64; m <<= 1) {
    contrib += __shfl_xor(contrib, m, 64);
    cnt     += __shfl_xor(cnt, m, 64);
  }
  if ((threadIdx.x & 63) == 0) { accs[threadIdx.x >> 6] = contrib; accn[threadIdx.x >> 6] = cnt; }
  __syncthreads();
  if (threadIdx.x == 0) {
    atomicAdd((float*)(ws + OFF_TOT), (accs[0] + accs[1]) + (accs[2] + accs[3]));
    atomicAdd((float*)(ws + OFF_CNT), (accn[0] + accn[1]) + (accn[2] + accn[3]));
  }
}

// ---------------- Kernel 4: final divide ----------------
__global__ __launch_bounds__(64) void finish2_k(const unsigned char* __restrict__ ws,
                                                float* __restrict__ out) {
  if (threadIdx.x == 0) {
    const float total = *(const float*)(ws + OFF_TOT);
    const float cnt   = *(const float*)(ws + OFF_CNT);
    out[0] = (cnt > 0.0f) ? total / (4.0f * cnt) : 0.0f;
  }
}

extern "C" void kernel_launch(void* const* d_in, const int* in_sizes, int n_in,
                              void* d_out, int out_size, void* d_ws, size_t ws_size,
                              hipStream_t stream) {
  const float* lv     = (const float*)d_in[0];   // (128,256,256) f32
  const float* protos = (const float*)d_in[1];   // (1024,256,1,1) f32
  const int*   gt     = (const int*)d_in[2];     // (128,256) i32
  (void)in_sizes; (void)n_in; (void)out_size; (void)ws_size;
  unsigned char* ws = (unsigned char*)d_ws;

  prep_k<<<256, 256, 0, stream>>>(protos, ws);
  main_k<<<1024, 256, 0, stream>>>(lv, ws);
  finish1_k<<<128, 256, 0, stream>>>(gt, ws);
  finish2_k<<<1, 64, 0, stream>>>(ws, (float*)d_out);
}

// Round 10
// 44.070 us; speedup vs baseline: 2.0613x; 1.4167x over previous
//
#include <hip/hip_runtime.h>
#include <hip/hip_bf16.h>
#include <stdint.h>

// Problem constants (fixed by setup_inputs)
#define KC   256      // concepts
#define DD   256      // feature dim
#define NPROT 1024    // KC*M
#define NQ   32768    // B*KC

// ws layout (bytes); ws_size = 256 MB. Total used ~2.6 MB.
#define OFF_TOT  0                        // float
#define OFF_CNT  8                        // float
#define OFF_PN   256                      // bf16 protos k-major: [16 kslabs][1024 rows][32B] (512 KB)
#define OFF_ACC  524544                   // float2[4 chunks][4 waves][32768 q] = 4 MB, collision-free
#define ACC_STRIDE 32768                  // float2 per (c,w) plane

#define LN2F    0.69314718055994531f
#define C10L2E  14.426950408889634f       // 10 * log2(e): folds 1/T into exp2 domain

typedef __bf16 bf16x8 __attribute__((ext_vector_type(8)));
typedef float  f32x16 __attribute__((ext_vector_type(16)));

static __device__ __forceinline__ unsigned short f2bf(float x) {
  __hip_bfloat16 h = __float2bfloat16(x);
  return __builtin_bit_cast(unsigned short, h);
}

// ---------------- Kernel 1: normalize protos -> bf16 k-major; zero scalars ----------------
__global__ __launch_bounds__(256) void prep_k(const float* __restrict__ protos,
                                              unsigned char* __restrict__ ws) {
  if (blockIdx.x == 0 && threadIdx.x == 0) {
    *(float*)(ws + OFF_TOT) = 0.0f;
    *(float*)(ws + OFF_CNT) = 0.0f;
  }
  const int w = threadIdx.x >> 6, lane = threadIdx.x & 63;
  const int r = blockIdx.x * 4 + w;                  // 256 blocks * 4 = 1024 rows
  const float4 v = ((const float4*)protos)[r * 64 + lane];
  float ss = v.x*v.x + v.y*v.y + v.z*v.z + v.w*v.w;
#pragma unroll
  for (int m = 1; m < 64; m <<= 1) ss += __shfl_xor(ss, m, 64);
  const float sc = 1.0f / fmaxf(sqrtf(ss), 1e-12f);
  uint2 p;
  p.x = (unsigned)f2bf(v.x * sc) | ((unsigned)f2bf(v.y * sc) << 16);
  p.y = (unsigned)f2bf(v.z * sc) | ((unsigned)f2bf(v.w * sc) << 16);
  // element e = lane*4.. -> slab = lane>>2, byte in slab-row = (lane&3)*8
  *(uint2*)(ws + OFF_PN + (lane >> 2) * 32768 + r * 32 + (lane & 3) * 8) = p;
}

// ---------------- Kernel 2: fused normalize(Q) + GEMM (4-chain ILP) + exp2/pos partials ----------------
// grid: 512 tiles (64 queries) x 4 chunks (256 protos) = 2048 blocks, 256 threads.
// No min-waves bound (r7/r8 lesson: forced caps split the unified RF and spill ~78 MB/dispatch).
__global__ __launch_bounds__(256) void main_k(const float* __restrict__ lv,
                                              unsigned char* __restrict__ ws) {
  __shared__ __align__(16) unsigned char Aq[64 * 512];  // 64 query rows, bf16, swizzled (32 KB)

  const int tid  = threadIdx.x;
  const int w    = tid >> 6;        // wave 0..3
  const int lane = tid & 63;
  const int hi   = lane >> 5;
  const int l31  = lane & 31;

  // XCD-chunked bijective swizzle (2048 % 8 == 0): all 4 chunk-blocks of a tile
  // land on one XCD -> shared L2 for their common 64 KB of lv.
  const int sbid = (int)(blockIdx.x & 7) * 256 + (int)(blockIdx.x >> 3);
  const int tile = sbid >> 2;                // 0..511 (64 queries each)
  const int c    = sbid & 3;                 // proto chunk of 256 rows

  // A-fragment bases: chains a0 = proto rows c*256 + w*64 + l31, a1 = +32
  const unsigned char* pn0 = ws + OFF_PN + (c * 256 + w * 64 + l31) * 32 + hi * 16;
  const unsigned char* pn1 = pn0 + 32 * 32;

  // depth-2 prefetch per chain (4 loads in flight), issued BEFORE phase 1
  bf16x8 pa0[2], pa1[2];
#pragma unroll
  for (int p = 0; p < 2; ++p) {
    pa0[p] = *(const bf16x8*)(pn0 + p * 32768);
    pa1[p] = *(const bf16x8*)(pn1 + p * 32768);
  }

  // ---- Phase 1: load + L2-normalize 64 query rows -> swizzled bf16 LDS ----
  const int grp = tid >> 4, sub = tid & 15;
#pragma unroll
  for (int t = 0; t < 4; ++t) {
    const int r = grp * 4 + t;               // row in tile 0..63
    const int q = tile * 64 + r;
    float4 vv[4];
#pragma unroll
    for (int u = 0; u < 4; ++u) vv[u] = ((const float4*)lv)[q * 64 + u * 16 + sub];
    float ss = 0.0f;
#pragma unroll
    for (int u = 0; u < 4; ++u)
      ss += vv[u].x*vv[u].x + vv[u].y*vv[u].y + vv[u].z*vv[u].z + vv[u].w*vv[u].w;
#pragma unroll
    for (int m = 1; m < 16; m <<= 1) ss += __shfl_xor(ss, m, 64);
    const float sc = 1.0f / fmaxf(sqrtf(ss), 1e-12f);
    const int swz = ((r & 7) << 4) ^ (((r >> 3) & 3) << 7);
#pragma unroll
    for (int u = 0; u < 4; ++u) {
      uint2 p;
      p.x = (unsigned)f2bf(vv[u].x * sc) | ((unsigned)f2bf(vv[u].y * sc) << 16);
      p.y = (unsigned)f2bf(vv[u].z * sc) | ((unsigned)f2bf(vv[u].w * sc) << 16);
      *(uint2*)(Aq + r * 512 + ((u * 128 + sub * 8) ^ swz)) = p;
    }
  }
  __syncthreads();

  f32x16 acc[2][2];
#pragma unroll
  for (int i = 0; i < 2; ++i)
#pragma unroll
    for (int j = 0; j < 2; ++j)
#pragma unroll
      for (int t = 0; t < 16; ++t) acc[i][j][t] = 0.0f;

  const int bswz = ((l31 & 7) << 4) ^ (((l31 >> 3) & 3) << 7);  // rows l31 / 32+l31 identical

  // ---- K loop: 16 steps, 4 independent MFMA chains, depth-2 ring per A-chain ----
#pragma unroll
  for (int k = 0; k < 16; ++k) {
    const bf16x8 a0 = pa0[k & 1];
    const bf16x8 a1 = pa1[k & 1];
    // prefetch k+2 ((k+2)&15 keeps the tail inside PN; those slots are never consumed)
    pa0[k & 1] = *(const bf16x8*)(pn0 + ((k + 2) & 15) * 32768);
    pa1[k & 1] = *(const bf16x8*)(pn1 + ((k + 2) & 15) * 32768);
    const int bc = (k * 32 + hi * 16) ^ bswz;
    const bf16x8 b0 = *(const bf16x8*)(Aq + l31 * 512 + bc);
    const bf16x8 b1 = *(const bf16x8*)(Aq + (32 + l31) * 512 + bc);
    acc[0][0] = __builtin_amdgcn_mfma_f32_32x32x16_bf16(a0, b0, acc[0][0], 0, 0, 0);
    acc[0][1] = __builtin_amdgcn_mfma_f32_32x32x16_bf16(a0, b1, acc[0][1], 0, 0, 0);
    acc[1][0] = __builtin_amdgcn_mfma_f32_32x32x16_bf16(a1, b0, acc[1][0], 0, 0, 0);
    acc[1][1] = __builtin_amdgcn_mfma_f32_32x32x16_bf16(a1, b1, acc[1][1], 0, 0, 0);
  }

  // ---- epilogue (r2-proven): y = sim*10*log2e; L += 2^y; P += y on positives ----
  float l_acc[2] = {0.f, 0.f}, p_acc[2] = {0.f, 0.f};
#pragma unroll
  for (int i = 0; i < 2; ++i) {
    const int r4base = c * 64 + w * 16 + i * 8 + hi;   // proto row>>2 = r4base + 2*g
#pragma unroll
    for (int j = 0; j < 2; ++j) {
      const int kq = (tile * 64 + j * 32 + l31) & (KC - 1);
      float l4[4] = {0.f, 0.f, 0.f, 0.f};
      float p4[4] = {0.f, 0.f, 0.f, 0.f};
#pragma unroll
      for (int g = 0; g < 4; ++g) {
        const float pm = (r4base + 2 * g == kq) ? 1.0f : 0.0f;
#pragma unroll
        for (int t = 0; t < 4; ++t) {
          const float y = acc[i][j][g * 4 + t] * C10L2E;
          l4[t] += __builtin_amdgcn_exp2f(y);
          p4[t] = fmaf(pm, y, p4[t]);
        }
      }
      l_acc[j] += (l4[0] + l4[1]) + (l4[2] + l4[3]);
      p_acc[j] += (p4[0] + p4[1]) + (p4[2] + p4[3]);
    }
  }

  // combine the two row-half lanes (lane ^ 32); ONE coalesced store per (q, chunk, wave)
#pragma unroll
  for (int j = 0; j < 2; ++j) {
    l_acc[j] += __shfl_xor(l_acc[j], 32, 64);
    p_acc[j] += __shfl_xor(p_acc[j], 32, 64);
  }
  if (hi == 0) {
    float2* accb = (float2*)(ws + OFF_ACC) + (c * 4 + w) * ACC_STRIDE;
#pragma unroll
    for (int j = 0; j < 2; ++j) {
      const int q = tile * 64 + j * 32 + l31;
      float2 v2; v2.x = l_acc[j]; v2.y = p_acc[j];
      accb[q] = v2;
    }
  }
}

// ---------------- Kernel 3: per-query contribution + count, grid sum into ws ----------------
__global__ __launch_bounds__(256) void finish1_k(const int* __restrict__ gt,
                                                 unsigned char* __restrict__ ws) {
  __shared__ float accs[4], accn[4];
  const int i = blockIdx.x * 256 + threadIdx.x;   // 128 blocks -> 32768
  float contrib = 0.0f, cnt = 0.0f;
  if (gt[i] == 1) {
    const float2* a = (const float2*)(ws + OFF_ACC);
    float L = 0.0f, P = 0.0f;
#pragma unroll
    for (int u = 0; u < 16; ++u) {           // 16 (c,w) planes, coalesced across threads
      const float2 v = a[u * ACC_STRIDE + i];
      L += v.x; P += v.y;
    }
    contrib = LN2F * (4.0f * __builtin_amdgcn_logf(L) - P);  // v_log_f32 = log2
    cnt = 1.0f;
  }
#pragma unroll
  for (int m = 1; m < 64; m <<= 1) {
    contrib += __shfl_xor(contrib, m, 64);
    cnt     += __shfl_xor(cnt, m, 64);
  }
  if ((threadIdx.x & 63) == 0) { accs[threadIdx.x >> 6] = contrib; accn[threadIdx.x >> 6] = cnt; }
  __syncthreads();
  if (threadIdx.x == 0) {
    atomicAdd((float*)(ws + OFF_TOT), (accs[0] + accs[1]) + (accs[2] + accs[3]));
    atomicAdd((float*)(ws + OFF_CNT), (accn[0] + accn[1]) + (accn[2] + accn[3]));
  }
}

// ---------------- Kernel 4: final divide ----------------
__global__ __launch_bounds__(64) void finish2_k(const unsigned char* __restrict__ ws,
                                                float* __restrict__ out) {
  if (threadIdx.x == 0) {
    const float total = *(const float*)(ws + OFF_TOT);
    const float cnt   = *(const float*)(ws + OFF_CNT);
    out[0] = (cnt > 0.0f) ? total / (4.0f * cnt) : 0.0f;
  }
}

extern "C" void kernel_launch(void* const* d_in, const int* in_sizes, int n_in,
                              void* d_out, int out_size, void* d_ws, size_t ws_size,
                              hipStream_t stream) {
  const float* lv     = (const float*)d_in[0];   // (128,256,256) f32
  const float* protos = (const float*)d_in[1];   // (1024,256,1,1) f32
  const int*   gt     = (const int*)d_in[2];     // (128,256) i32
  (void)in_sizes; (void)n_in; (void)out_size; (void)ws_size;
  unsigned char* ws = (unsigned char*)d_ws;

  prep_k<<<256, 256, 0, stream>>>(protos, ws);
  main_k<<<2048, 256, 0, stream>>>(lv, ws);
  finish1_k<<<128, 256, 0, stream>>>(gt, ws);
  finish2_k<<<1, 64, 0, stream>>>(ws, (float*)d_out);
}